// Round 1
// baseline (1191.994 us; speedup 1.0000x reference)
//
#include <hip/hip_runtime.h>

#define B_ 2048
#define S_ 50
#define E_ 300
#define T_ 8
#define NPAIR 44850
#define KPAD 45056              // NPAIR padded to multiple of 32*KSPLIT
#define KSPLIT 8
#define KPER (KPAD / KSPLIT)    // 5632
#define NCHUNK (KPER / 32)      // 176
#define PADSCORE (-4294967295.0f)

typedef _Float16 h8 __attribute__((ext_vector_type(8)));
typedef float f4 __attribute__((ext_vector_type(4)));

// ---------- prep: g[p] = dot(v[i],v[j]), ij[p] = i | j<<16 ----------
__global__ void k_gij(const float* __restrict__ v, float* __restrict__ g,
                      unsigned* __restrict__ ij) {
  int i = blockIdx.x;
  if (i < E_) {
    float vi0 = v[i*4+0], vi1 = v[i*4+1], vi2 = v[i*4+2], vi3 = v[i*4+3];
    int base = i*(2*E_ - i - 1)/2;
    for (int j = i + 1 + (int)threadIdx.x; j < E_; j += blockDim.x) {
      float s = vi0*v[j*4+0] + vi1*v[j*4+1] + vi2*v[j*4+2] + vi3*v[j*4+3];
      int p = base + (j - i - 1);
      g[p] = s;
      ij[p] = (unsigned)i | ((unsigned)j << 16);
    }
  } else {  // padding entries
    for (int p = NPAIR + (int)threadIdx.x; p < KPAD; p += blockDim.x) {
      g[p] = 0.f;
      ij[p] = 0u | (1u << 16);
    }
  }
}

// ---------- prep: Wg[e][p] = f16(fc7_w[e][p] * g[p]), zero-padded ----------
__global__ void k_wg(const float* __restrict__ w7, const float* __restrict__ g,
                     _Float16* __restrict__ Wg) {
  int e = blockIdx.y;
  int p = blockIdx.x * 256 + threadIdx.x;
  float val = 0.f;
  if (e < E_ && p < NPAIR) val = w7[(size_t)e*NPAIR + p] * g[p];
  Wg[(size_t)e*KPAD + p] = (_Float16)val;
}

// ---------- attn pass A: a1/a2 = relu(x@w^T + b), sumabs ----------
__global__ __launch_bounds__(256) void k_attnA(
    const float* __restrict__ x, const float* __restrict__ w1, const float* __restrict__ b1,
    const float* __restrict__ w3, const float* __restrict__ b3,
    float* __restrict__ a1, float* __restrict__ a2, float* __restrict__ sabs) {
  __shared__ float wL[16][E_];
  __shared__ float xL[E_];
  __shared__ float bL[16];
  int b = blockIdx.x;
  for (int idx = threadIdx.x; idx < 16*E_; idx += 256) {
    int t = idx / E_, e = idx - t*E_;
    wL[t][e] = (t < 8) ? w1[t*E_ + e] : w3[(t-8)*E_ + e];
  }
  if (threadIdx.x < 16)
    bL[threadIdx.x] = (threadIdx.x < 8) ? b1[threadIdx.x] : b3[threadIdx.x - 8];
  int wave = threadIdx.x >> 6, lane = threadIdx.x & 63;
  for (int s = 0; s < S_; s++) {
    __syncthreads();
    for (int e = threadIdx.x; e < E_; e += 256)
      xL[e] = x[((size_t)b*S_ + s)*E_ + e];
    __syncthreads();
    float acc[4] = {0.f,0.f,0.f,0.f};
    float sa = 0.f;
    for (int e = lane; e < E_; e += 64) {
      float xv = xL[e];
      if (wave == 0) sa += fabsf(xv);
      #pragma unroll
      for (int t = 0; t < 4; t++) acc[t] += xv * wL[wave*4 + t][e];
    }
    #pragma unroll
    for (int off = 32; off; off >>= 1) {
      #pragma unroll
      for (int t = 0; t < 4; t++) acc[t] += __shfl_xor(acc[t], off);
      sa += __shfl_xor(sa, off);
    }
    if (lane == 0) {
      #pragma unroll
      for (int t = 0; t < 4; t++) {
        int tt = wave*4 + t;
        float val = fmaxf(acc[t] + bL[tt], 0.f);
        float* dst = (tt < 8) ? a1 : a2;
        dst[((size_t)b*S_ + s)*T_ + (tt & 7)] = val;
      }
      if (wave == 0) sabs[(size_t)b*S_ + s] = sa;
    }
  }
}

// ---------- attn BN stats over (B,T) per s ----------
__global__ void k_attnstats(const float* __restrict__ a1, const float* __restrict__ a2,
                            float* __restrict__ sstat) {
  int s = blockIdx.x, pool = blockIdx.y;
  const float* a = pool ? a2 : a1;
  float sum = 0.f, sq = 0.f;
  for (int b = threadIdx.x; b < B_; b += blockDim.x) {
    const float* row = &a[((size_t)b*S_ + s)*T_];
    #pragma unroll
    for (int t = 0; t < 8; t++) { float v = row[t]; sum += v; sq += v*v; }
  }
  __shared__ float rs[2][4];
  int wave = threadIdx.x >> 6, lane = threadIdx.x & 63;
  #pragma unroll
  for (int off = 32; off; off >>= 1) { sum += __shfl_xor(sum, off); sq += __shfl_xor(sq, off); }
  if (lane == 0) { rs[0][wave] = sum; rs[1][wave] = sq; }
  __syncthreads();
  if (threadIdx.x == 0) {
    float S = rs[0][0]+rs[0][1]+rs[0][2]+rs[0][3];
    float Q = rs[1][0]+rs[1][1]+rs[1][2]+rs[1][3];
    float n = (float)(B_*T_);
    float m = S / n;
    float var = Q / n - m*m;
    sstat[(pool*S_ + s)*2 + 0] = m;
    sstat[(pool*S_ + s)*2 + 1] = rsqrtf(var + 1e-5f);
  }
}

// ---------- scores + softmax + weighted pool -> h [B,600] ----------
__global__ __launch_bounds__(256) void k_pool(
    const float* __restrict__ x, const float* __restrict__ a1, const float* __restrict__ a2,
    const float* __restrict__ sabs, const float* __restrict__ sstat,
    const float* __restrict__ q1, const float* __restrict__ q2, float* __restrict__ h) {
  int b = blockIdx.x;
  __shared__ float w1s[S_], w2s[S_];
  int tid = threadIdx.x;
  if (tid < S_) {
    float sc1 = 0.f, sc2 = 0.f;
    const float* r1 = &a1[((size_t)b*S_ + tid)*T_];
    const float* r2 = &a2[((size_t)b*S_ + tid)*T_];
    float m1 = sstat[(0*S_ + tid)*2], rr1 = sstat[(0*S_ + tid)*2 + 1];
    float m2 = sstat[(1*S_ + tid)*2], rr2 = sstat[(1*S_ + tid)*2 + 1];
    #pragma unroll
    for (int t = 0; t < 8; t++) {
      sc1 += (r1[t] - m1) * rr1 * q1[t];
      sc2 += (r2[t] - m2) * rr2 * q2[t];
    }
    if (sabs[(size_t)b*S_ + tid] == 0.f) { sc1 = PADSCORE; sc2 = PADSCORE; }
    w1s[tid] = sc1; w2s[tid] = sc2;
  }
  __syncthreads();
  if (tid < 64) {
    float v1 = (tid < S_) ? w1s[tid] : -3.0e38f;
    float v2 = (tid < S_) ? w2s[tid] : -3.0e38f;
    float m1 = v1, m2 = v2;
    #pragma unroll
    for (int off = 32; off; off >>= 1) {
      m1 = fmaxf(m1, __shfl_xor(m1, off));
      m2 = fmaxf(m2, __shfl_xor(m2, off));
    }
    float e1 = (tid < S_) ? expf(v1 - m1) : 0.f;
    float e2 = (tid < S_) ? expf(v2 - m2) : 0.f;
    float s1 = e1, s2 = e2;
    #pragma unroll
    for (int off = 32; off; off >>= 1) { s1 += __shfl_xor(s1, off); s2 += __shfl_xor(s2, off); }
    if (tid < S_) { w1s[tid] = e1 / s1; w2s[tid] = e2 / s2; }
  }
  __syncthreads();
  for (int e = tid; e < E_; e += 256) {
    float p1 = 0.f, p2 = 0.f;
    for (int s = 0; s < S_; s++) {
      float xv = x[((size_t)b*S_ + s)*E_ + e];
      p1 += xv * w1s[s];
      p2 += xv * w2s[s];
    }
    h[(size_t)b*600 + e]       = p1;
    h[(size_t)b*600 + 300 + e] = p2;
  }
}

// ---------- generic fp32 GEMM: Y[M,N] = X[M,K] @ W[N,K]^T (+bias) ----------
__global__ __launch_bounds__(256) void k_gemm_nt(
    const float* __restrict__ X, const float* __restrict__ W, const float* __restrict__ bias,
    float* __restrict__ Y, int M, int N, int K) {
  __shared__ float Xs[16][65];
  __shared__ float Wt[16][65];
  int bm = blockIdx.y * 64, bn = blockIdx.x * 64;
  int tx = threadIdx.x & 15, ty = threadIdx.x >> 4;
  float acc[4][4] = {};
  for (int k0 = 0; k0 < K; k0 += 16) {
    for (int idx = threadIdx.x; idx < 1024; idx += 256) {
      int m = idx >> 4, kk = idx & 15;
      int gk = k0 + kk;
      Xs[kk][m] = (gk < K) ? X[(size_t)(bm + m)*K + gk] : 0.f;
      int gn = bn + m;
      Wt[kk][m] = (gn < N && gk < K) ? W[(size_t)gn*K + gk] : 0.f;
    }
    __syncthreads();
    #pragma unroll
    for (int kk = 0; kk < 16; kk++) {
      float xr[4], wr[4];
      #pragma unroll
      for (int i = 0; i < 4; i++) xr[i] = Xs[kk][ty*4 + i];
      #pragma unroll
      for (int j = 0; j < 4; j++) wr[j] = Wt[kk][tx*4 + j];
      #pragma unroll
      for (int i = 0; i < 4; i++)
        #pragma unroll
        for (int j = 0; j < 4; j++) acc[i][j] = fmaf(xr[i], wr[j], acc[i][j]);
    }
    __syncthreads();
  }
  #pragma unroll
  for (int i = 0; i < 4; i++) {
    int gm = bm + ty*4 + i;
    #pragma unroll
    for (int j = 0; j < 4; j++) {
      int gn = bn + tx*4 + j;
      if (gn < N) Y[(size_t)gm*N + gn] = acc[i][j] + (bias ? bias[gn] : 0.f);
    }
  }
}

// ---------- column stats (mean/rstd over batch): partial then finalize ----------
__global__ void k_colstat_part(const float* __restrict__ X, float* __restrict__ part,
                               int M, int N) {
  int nblk = gridDim.x;
  int rows = (M + nblk - 1) / nblk;
  int r0 = blockIdx.x * rows, r1 = min(M, r0 + rows);
  for (int c = threadIdx.x; c < N; c += blockDim.x) {
    float s = 0.f, q = 0.f;
    for (int r = r0; r < r1; r++) { float v = X[(size_t)r*N + c]; s += v; q += v*v; }
    part[((size_t)blockIdx.x*N + c)*2 + 0] = s;
    part[((size_t)blockIdx.x*N + c)*2 + 1] = q;
  }
}

__global__ void k_colstat_fin(const float* __restrict__ part, float* __restrict__ stat,
                              int N, int nparts, int M) {
  int c = threadIdx.x;
  if (c >= N) return;
  float s = 0.f, q = 0.f;
  for (int p = 0; p < nparts; p++) {
    s += part[((size_t)p*N + c)*2 + 0];
    q += part[((size_t)p*N + c)*2 + 1];
  }
  float m = s / (float)M;
  float var = q / (float)M - m*m;
  stat[c*2 + 0] = m;
  stat[c*2 + 1] = rsqrtf(var + 1e-5f);
}

// ---------- normalize h5 (writes f32 + padded f16 copy) ----------
__global__ void k_norm_h5(const float* __restrict__ X, const float* __restrict__ stat,
                          float* __restrict__ h5, _Float16* __restrict__ h5h) {
  int idx = blockIdx.x * 256 + threadIdx.x;
  if (idx >= B_*320) return;
  int b = idx / 320, c = idx - b*320;
  if (c < E_) {
    float v = (X[(size_t)b*E_ + c] - stat[c*2]) * stat[c*2 + 1];
    h5[(size_t)b*E_ + c] = v;
    h5h[idx] = (_Float16)v;
  } else {
    h5h[idx] = (_Float16)0.f;
  }
}

// ---------- normalize into hcat at column offset ----------
__global__ void k_norm_to(const float* __restrict__ X, const float* __restrict__ stat,
                          float* __restrict__ Y, int off) {
  int idx = blockIdx.x * 256 + threadIdx.x;
  if (idx >= B_*E_) return;
  int b = idx / E_, c = idx - b*E_;
  Y[(size_t)b*600 + off + c] = (X[idx] - stat[c*2]) * stat[c*2 + 1];
}

// ---------- big MFMA GEMM: part[ks][b][e] = sum_p A[b,p] * Wg[e,p] ----------
__global__ __launch_bounds__(256, 2) void k_bigmm(
    const _Float16* __restrict__ Wg, const _Float16* __restrict__ h5h,
    const unsigned* __restrict__ ij, float* __restrict__ part) {
  __shared__ _Float16 h5T[320][72];   // [col i][m], padded stride for banks
  __shared__ _Float16 Ws[160][40];    // [n][k], +8 pad
  __shared__ _Float16 As[64][40];     // [m][k], +8 pad
  const int ks = blockIdx.x, mblk = blockIdx.y, nblk = blockIdx.z;
  const int tid = threadIdx.x;
  const int wave = tid >> 6, lane = tid & 63, quad = lane >> 4, l16 = lane & 15;
  const int wm = wave >> 1, wn = wave & 1;

  {
    const _Float16* src = h5h + (size_t)mblk * 64 * 320;
    for (int u = tid; u < 64*320; u += 256) {
      int m = u / 320, c = u - m*320;
      h5T[c][m] = src[u];
    }
  }
  __syncthreads();

  f4 acc[2][5];
  #pragma unroll
  for (int i = 0; i < 2; i++)
    #pragma unroll
    for (int j = 0; j < 5; j++) acc[i][j] = (f4){0.f, 0.f, 0.f, 0.f};

  const int kb = tid & 31;
  const int m0 = (tid >> 5) * 8;
  const int p00 = ks * KPER;

  for (int ch = 0; ch < NCHUNK; ch++) {
    const int pc = p00 + ch*32;
    // stage W tile: 160 rows x 32 k (f16), 640 x 16B units
    #pragma unroll
    for (int it = 0; it < 3; it++) {
      int u = tid + it*256;
      if (u < 640) {
        int n = u >> 2, seg = u & 3;
        *(float4*)&Ws[n][seg*8] =
            *(const float4*)&Wg[(size_t)(nblk*160 + n)*KPAD + pc + seg*8];
      }
    }
    // build A column kb for 8 m's (vectorized over m)
    {
      unsigned u = ij[pc + kb];
      int pi = u & 0xffff, pj = u >> 16;
      h8 vi = *(const h8*)&h5T[pi][m0];
      h8 vj = *(const h8*)&h5T[pj][m0];
      h8 pr = vi * vj;
      #pragma unroll
      for (int t = 0; t < 8; t++) As[m0 + t][kb] = pr[t];
    }
    __syncthreads();
    h8 af[2], bf[5];
    #pragma unroll
    for (int mi = 0; mi < 2; mi++) af[mi] = *(const h8*)&As[wm*32 + mi*16 + l16][quad*8];
    #pragma unroll
    for (int nt = 0; nt < 5; nt++) bf[nt] = *(const h8*)&Ws[wn*80 + nt*16 + l16][quad*8];
    #pragma unroll
    for (int mi = 0; mi < 2; mi++)
      #pragma unroll
      for (int nt = 0; nt < 5; nt++)
        acc[mi][nt] = __builtin_amdgcn_mfma_f32_16x16x32_f16(af[mi], bf[nt], acc[mi][nt], 0, 0, 0);
    __syncthreads();
  }

  float* dst = part + (size_t)ks * (B_*E_);
  #pragma unroll
  for (int mi = 0; mi < 2; mi++) {
    int b = mblk*64 + wm*32 + mi*16 + quad*4;
    #pragma unroll
    for (int nt = 0; nt < 5; nt++) {
      int e = nblk*160 + wn*80 + nt*16 + l16;
      if (e < E_) {
        #pragma unroll
        for (int r = 0; r < 4; r++)
          dst[(size_t)(b + r)*E_ + e] = acc[mi][nt][r];
      }
    }
  }
}

// ---------- reduce split-K partials ----------
__global__ void k_reduce(const float* __restrict__ part, float* __restrict__ out) {
  int idx = blockIdx.x * 256 + threadIdx.x;
  if (idx >= B_*E_) return;
  float s = 0.f;
  #pragma unroll
  for (int k2 = 0; k2 < KSPLIT; k2++) s += part[(size_t)k2*(B_*E_) + idx];
  out[idx] = s;
}

extern "C" void kernel_launch(void* const* d_in, const int* in_sizes, int n_in,
                              void* d_out, int out_size, void* d_ws, size_t ws_size,
                              hipStream_t stream) {
  const float* x    = (const float*)d_in[0];
  const float* lemb = (const float*)d_in[1];
  const float* fc1w = (const float*)d_in[2];
  const float* fc1b = (const float*)d_in[3];
  const float* q1   = (const float*)d_in[4];
  const float* fc3w = (const float*)d_in[5];
  const float* fc3b = (const float*)d_in[6];
  const float* q2   = (const float*)d_in[7];
  const float* fc5w = (const float*)d_in[8];
  const float* fc6w = (const float*)d_in[10];
  const float* fc7w = (const float*)d_in[12];
  const float* fc8w = (const float*)d_in[14];
  const float* fc8b = (const float*)d_in[15];
  const float* v    = (const float*)d_in[16];
  float* out = (float*)d_out;
  (void)in_sizes; (void)n_in; (void)out_size; (void)ws_size;

  char* base = (char*)d_ws;
  size_t off = 0;
  auto alloc = [&](size_t nbytes) -> char* {
    char* p = base + off;
    off = (off + nbytes + 255) & ~(size_t)255;
    return p;
  };
  // persistent buffers
  unsigned*  ij    = (unsigned*) alloc((size_t)KPAD * 4);
  _Float16*  Wg    = (_Float16*) alloc((size_t)320 * KPAD * 2);
  _Float16*  h5h   = (_Float16*) alloc((size_t)B_ * 320 * 2);
  float*     hcat  = (float*)    alloc((size_t)B_ * 600 * 4);
  float*     h7pre = (float*)    alloc((size_t)B_ * E_ * 4);
  float*     out8  = (float*)    alloc((size_t)B_ * E_ * 4);
  float*     cpart = (float*)    alloc((size_t)16 * E_ * 2 * 4);
  float*     cstat = (float*)    alloc((size_t)E_ * 2 * 4);
  // scratch union: phase-1 temporaries overlap with split-K partials
  size_t part_bytes = (size_t)KSPLIT * B_ * E_ * 4;            // 19.66 MB
  char* scratch = alloc(part_bytes);
  float* g     = (float*)scratch;                               // 180224 B
  float* a1    = (float*)(scratch + 180224);
  float* a2    = a1 + (size_t)B_*S_*T_;
  float* sabs  = a2 + (size_t)B_*S_*T_;
  float* sstat = sabs + (size_t)B_*S_;
  float* h     = sstat + 256;
  float* h5pre = h + (size_t)B_*600;
  float* h5    = h5pre + (size_t)B_*E_;
  float* h6pre = h5 + (size_t)B_*E_;
  float* part  = (float*)scratch;   // reused after phase-1 temporaries are dead

  // 1-2: pair prep + Wg = f16(fc7_w * g)
  hipLaunchKernelGGL(k_gij, dim3(E_ + 1), dim3(256), 0, stream, v, g, ij);
  hipLaunchKernelGGL(k_wg, dim3(KPAD/256, 320), dim3(256), 0, stream, fc7w, g, Wg);
  // 3-5: attention pools
  hipLaunchKernelGGL(k_attnA, dim3(B_), dim3(256), 0, stream, x, fc1w, fc1b, fc3w, fc3b, a1, a2, sabs);
  hipLaunchKernelGGL(k_attnstats, dim3(S_, 2), dim3(256), 0, stream, a1, a2, sstat);
  hipLaunchKernelGGL(k_pool, dim3(B_), dim3(256), 0, stream, x, a1, a2, sabs, sstat, q1, q2, h);
  // 6-8: fc5 + BN -> h5 (f32 + f16)   (bias absorbed by BN)
  hipLaunchKernelGGL(k_gemm_nt, dim3(5, 32), dim3(256), 0, stream, h, fc5w, (const float*)nullptr, h5pre, B_, E_, 600);
  hipLaunchKernelGGL(k_colstat_part, dim3(16), dim3(320), 0, stream, h5pre, cpart, B_, E_);
  hipLaunchKernelGGL(k_colstat_fin, dim3(1), dim3(320), 0, stream, cpart, cstat, E_, 16, B_);
  hipLaunchKernelGGL(k_norm_h5, dim3((B_*320)/256), dim3(256), 0, stream, h5pre, cstat, h5, h5h);
  // 9-11: fc6 + BN -> hcat[:, :300]
  hipLaunchKernelGGL(k_gemm_nt, dim3(5, 32), dim3(256), 0, stream, h5, fc6w, (const float*)nullptr, h6pre, B_, E_, E_);
  hipLaunchKernelGGL(k_colstat_part, dim3(16), dim3(320), 0, stream, h6pre, cpart, B_, E_);
  hipLaunchKernelGGL(k_colstat_fin, dim3(1), dim3(320), 0, stream, cpart, cstat, E_, 16, B_);
  hipLaunchKernelGGL(k_norm_to, dim3((B_*E_)/256), dim3(256), 0, stream, h6pre, cstat, hcat, 0);
  // 12-15: cross-feature GEMM (f16 MFMA, split-K) + BN -> hcat[:, 300:]
  hipLaunchKernelGGL(k_bigmm, dim3(KSPLIT, 32, 2), dim3(256), 0, stream, Wg, h5h, ij, part);
  hipLaunchKernelGGL(k_reduce, dim3((B_*E_)/256), dim3(256), 0, stream, part, h7pre);
  hipLaunchKernelGGL(k_colstat_part, dim3(16), dim3(320), 0, stream, h7pre, cpart, B_, E_);
  hipLaunchKernelGGL(k_colstat_fin, dim3(1), dim3(320), 0, stream, cpart, cstat, E_, 16, B_);
  hipLaunchKernelGGL(k_norm_to, dim3((B_*E_)/256), dim3(256), 0, stream, h7pre, cstat, hcat, 300);
  // 16-17: fc8 + label projection
  hipLaunchKernelGGL(k_gemm_nt, dim3(5, 32), dim3(256), 0, stream, hcat, fc8w, fc8b, out8, B_, E_, 600);
  hipLaunchKernelGGL(k_gemm_nt, dim3(16, 32), dim3(256), 0, stream, out8, lemb, (const float*)nullptr, out, B_, 1000, E_);
}

// Round 2
// 1054.793 us; speedup vs baseline: 1.1301x; 1.1301x over previous
//
#include <hip/hip_runtime.h>

#define B_ 2048
#define S_ 50
#define E_ 300
#define NPAIR 44850
#define KSPLIT 8
#define R_ (B_ * S_)            // 102400 rows for attn fc
#define PADSCORE (-4294967295.0f)

typedef _Float16 h8 __attribute__((ext_vector_type(8)));
typedef float f4 __attribute__((ext_vector_type(4)));

// ---------- chunk metadata: each 32-wide k-chunk has a single i, 8-aligned j0 ----------
// row i: j_s = (i+1)&~7, len = ceil((300-j_s)/32)*32, chunk c covers j in [j_s+32c, j_s+32c+31]
__global__ void k_meta(int* __restrict__ meta) {
  __shared__ int cnt[304], start[304];
  int i = threadIdx.x;
  if (i < 299) {
    int js = (i + 1) & ~7;
    cnt[i] = (300 - js + 31) >> 5;
  }
  __syncthreads();
  if (threadIdx.x == 0) {
    int s = 0;
    for (int r = 0; r < 299; r++) { start[r] = s; s += cnt[r]; }
  }
  __syncthreads();
  if (i < 299) {
    int js = (i + 1) & ~7;
    for (int c = 0; c < cnt[i]; c++)
      meta[start[i] + c] = i | ((js + 32 * c) << 16);
  }
}

// ---------- Wg[e][ch*32+kk] = f16( fc7_w[e, p(i,j)] * (v_i . v_j) ), zeros on pads ----------
__global__ __launch_bounds__(256) void k_wg2(
    const float* __restrict__ w7, const float* __restrict__ v,
    const int* __restrict__ meta, _Float16* __restrict__ Wg, int kpad2) {
  int ch = blockIdx.x;
  int mt = meta[ch];
  int i = mt & 0xffff, j0 = mt >> 16;
  int kk = threadIdx.x & 31;
  int j = j0 + kk;
  bool valid = (j > i) && (j < 300);
  int p = 0;
  float g = 0.f;
  if (valid) {
    p = i * (599 - i) / 2 + (j - i - 1);
    g = v[i*4+0]*v[j*4+0] + v[i*4+1]*v[j*4+1] + v[i*4+2]*v[j*4+2] + v[i*4+3]*v[j*4+3];
  }
  #pragma unroll
  for (int rep = 0; rep < 2; rep++) {
    int e = blockIdx.y * 16 + (threadIdx.x >> 5) + rep * 8;
    float val = (valid && e < 300) ? w7[(size_t)e * NPAIR + p] * g : 0.f;
    Wg[(size_t)e * kpad2 + ch * 32 + kk] = (_Float16)val;
  }
}

// ---------- attn fc: a[r][16] = relu(x[r] @ w^T + b), sabs[r] = sum|x[r]| ----------
// block = 128 rows; thread (rg 0..31, tg 0..7) does rows {rg+32k2} x t-pair {2tg,2tg+1}
__global__ __launch_bounds__(256) void k_attn2(
    const float* __restrict__ x, const float* __restrict__ w1, const float* __restrict__ b1,
    const float* __restrict__ w3, const float* __restrict__ b3,
    float* __restrict__ a, float* __restrict__ sabs) {
  __shared__ float xs[128][68];
  __shared__ float wL[16][308];
  const int tid = threadIdx.x;
  const int r0 = blockIdx.x * 128;
  // stage weights [16][300]
  for (int u = tid; u < 16 * 75; u += 256) {
    int t = u / 75, q = u - t * 75;
    float4 v4 = (t < 8) ? *(const float4*)&w1[t * 300 + q * 4]
                        : *(const float4*)&w3[(t - 8) * 300 + q * 4];
    *(float4*)&wL[t][q * 4] = v4;
  }
  const int rg = tid >> 3, tg = tid & 7;
  float acc[4][2] = {};
  float sa[4] = {};
  for (int k0 = 0; k0 < 300; k0 += 64) {
    int w = min(64, 300 - k0);   // 64,64,64,64,44
    __syncthreads();
    #pragma unroll
    for (int it = 0; it < 8; it++) {
      int u = tid + it * 256;    // < 2048 = 128 rows x 16 float4
      int r = u >> 4, q = u & 15;
      float4 v4 = {0.f, 0.f, 0.f, 0.f};
      if (q * 4 < w) v4 = *(const float4*)&x[(size_t)(r0 + r) * 300 + k0 + q * 4];
      *(float4*)&xs[r][q * 4] = v4;
    }
    __syncthreads();
    for (int q = 0; q < (w >> 2); q++) {
      float4 w0 = *(float4*)&wL[tg * 2][k0 + q * 4];
      float4 w1v = *(float4*)&wL[tg * 2 + 1][k0 + q * 4];
      #pragma unroll
      for (int k2 = 0; k2 < 4; k2++) {
        float4 xv = *(float4*)&xs[rg + 32 * k2][q * 4];
        acc[k2][0] += xv.x * w0.x + xv.y * w0.y + xv.z * w0.z + xv.w * w0.w;
        acc[k2][1] += xv.x * w1v.x + xv.y * w1v.y + xv.z * w1v.z + xv.w * w1v.w;
        if (tg == 0)
          sa[k2] += fabsf(xv.x) + fabsf(xv.y) + fabsf(xv.z) + fabsf(xv.w);
      }
    }
  }
  int t0 = tg * 2;
  float bb0 = (t0 < 8) ? b1[t0] : b3[t0 - 8];
  float bb1 = (t0 + 1 < 8) ? b1[t0 + 1] : b3[t0 + 1 - 8];
  #pragma unroll
  for (int k2 = 0; k2 < 4; k2++) {
    size_t r = r0 + rg + 32 * k2;
    a[r * 16 + t0]     = fmaxf(acc[k2][0] + bb0, 0.f);
    a[r * 16 + t0 + 1] = fmaxf(acc[k2][1] + bb1, 0.f);
    if (tg == 0) sabs[r] = sa[k2];
  }
}

// ---------- attn BN stats over (B,T) per s ----------
__global__ void k_attnstats(const float* __restrict__ a, float* __restrict__ sstat) {
  int s = blockIdx.x, pool = blockIdx.y;
  float sum = 0.f, sq = 0.f;
  for (int b = threadIdx.x; b < B_; b += blockDim.x) {
    const float* row = &a[((size_t)b * S_ + s) * 16 + pool * 8];
    #pragma unroll
    for (int t = 0; t < 8; t++) { float v = row[t]; sum += v; sq += v * v; }
  }
  __shared__ float rs[2][4];
  int wave = threadIdx.x >> 6, lane = threadIdx.x & 63;
  #pragma unroll
  for (int off = 32; off; off >>= 1) { sum += __shfl_xor(sum, off); sq += __shfl_xor(sq, off); }
  if (lane == 0) { rs[0][wave] = sum; rs[1][wave] = sq; }
  __syncthreads();
  if (threadIdx.x == 0) {
    float S = rs[0][0] + rs[0][1] + rs[0][2] + rs[0][3];
    float Q = rs[1][0] + rs[1][1] + rs[1][2] + rs[1][3];
    float n = (float)(B_ * 8);
    float m = S / n;
    float var = Q / n - m * m;
    sstat[(pool * S_ + s) * 2 + 0] = m;
    sstat[(pool * S_ + s) * 2 + 1] = rsqrtf(var + 1e-5f);
  }
}

// ---------- scores + softmax + weighted pool -> h [B,600] ----------
__global__ __launch_bounds__(256) void k_pool(
    const float* __restrict__ x, const float* __restrict__ a,
    const float* __restrict__ sabs, const float* __restrict__ sstat,
    const float* __restrict__ q1, const float* __restrict__ q2, float* __restrict__ h) {
  int b = blockIdx.x;
  __shared__ float w1s[S_], w2s[S_];
  int tid = threadIdx.x;
  if (tid < S_) {
    float sc1 = 0.f, sc2 = 0.f;
    const float* r1 = &a[((size_t)b * S_ + tid) * 16];
    const float* r2 = r1 + 8;
    float m1 = sstat[(0 * S_ + tid) * 2], rr1 = sstat[(0 * S_ + tid) * 2 + 1];
    float m2 = sstat[(1 * S_ + tid) * 2], rr2 = sstat[(1 * S_ + tid) * 2 + 1];
    #pragma unroll
    for (int t = 0; t < 8; t++) {
      sc1 += (r1[t] - m1) * rr1 * q1[t];
      sc2 += (r2[t] - m2) * rr2 * q2[t];
    }
    if (sabs[(size_t)b * S_ + tid] == 0.f) { sc1 = PADSCORE; sc2 = PADSCORE; }
    w1s[tid] = sc1; w2s[tid] = sc2;
  }
  __syncthreads();
  if (tid < 64) {
    float v1 = (tid < S_) ? w1s[tid] : -3.0e38f;
    float v2 = (tid < S_) ? w2s[tid] : -3.0e38f;
    float m1 = v1, m2 = v2;
    #pragma unroll
    for (int off = 32; off; off >>= 1) {
      m1 = fmaxf(m1, __shfl_xor(m1, off));
      m2 = fmaxf(m2, __shfl_xor(m2, off));
    }
    float e1 = (tid < S_) ? expf(v1 - m1) : 0.f;
    float e2 = (tid < S_) ? expf(v2 - m2) : 0.f;
    float s1 = e1, s2 = e2;
    #pragma unroll
    for (int off = 32; off; off >>= 1) { s1 += __shfl_xor(s1, off); s2 += __shfl_xor(s2, off); }
    if (tid < S_) { w1s[tid] = e1 / s1; w2s[tid] = e2 / s2; }
  }
  __syncthreads();
  for (int e = tid; e < E_; e += 256) {
    float p1 = 0.f, p2 = 0.f;
    for (int s = 0; s < S_; s++) {
      float xv = x[((size_t)b * S_ + s) * E_ + e];
      p1 += xv * w1s[s];
      p2 += xv * w2s[s];
    }
    h[(size_t)b * 600 + e]       = p1;
    h[(size_t)b * 600 + 300 + e] = p2;
  }
}

// ---------- generic fp32 GEMM: Y[M,N] = X[M,K] @ W[N,K]^T (+bias) ----------
__global__ __launch_bounds__(256) void k_gemm_nt(
    const float* __restrict__ X, const float* __restrict__ W, const float* __restrict__ bias,
    float* __restrict__ Y, int M, int N, int K) {
  __shared__ float Xs[16][65];
  __shared__ float Wt[16][65];
  int bm = blockIdx.y * 64, bn = blockIdx.x * 64;
  int tx = threadIdx.x & 15, ty = threadIdx.x >> 4;
  float acc[4][4] = {};
  for (int k0 = 0; k0 < K; k0 += 16) {
    for (int idx = threadIdx.x; idx < 1024; idx += 256) {
      int m = idx >> 4, kk = idx & 15;
      int gk = k0 + kk;
      Xs[kk][m] = (gk < K) ? X[(size_t)(bm + m) * K + gk] : 0.f;
      int gn = bn + m;
      Wt[kk][m] = (gn < N && gk < K) ? W[(size_t)gn * K + gk] : 0.f;
    }
    __syncthreads();
    #pragma unroll
    for (int kk = 0; kk < 16; kk++) {
      float xr[4], wr[4];
      #pragma unroll
      for (int i = 0; i < 4; i++) xr[i] = Xs[kk][ty * 4 + i];
      #pragma unroll
      for (int j = 0; j < 4; j++) wr[j] = Wt[kk][tx * 4 + j];
      #pragma unroll
      for (int i = 0; i < 4; i++)
        #pragma unroll
        for (int j = 0; j < 4; j++) acc[i][j] = fmaf(xr[i], wr[j], acc[i][j]);
    }
    __syncthreads();
  }
  #pragma unroll
  for (int i = 0; i < 4; i++) {
    int gm = bm + ty * 4 + i;
    #pragma unroll
    for (int j = 0; j < 4; j++) {
      int gn = bn + tx * 4 + j;
      if (gn < N) Y[(size_t)gm * N + gn] = acc[i][j] + (bias ? bias[gn] : 0.f);
    }
  }
}

// ---------- column stats (mean/rstd over batch) ----------
__global__ void k_colstat_part(const float* __restrict__ X, float* __restrict__ part,
                               int M, int N) {
  int nblk = gridDim.x;
  int rows = (M + nblk - 1) / nblk;
  int r0 = blockIdx.x * rows, r1 = min(M, r0 + rows);
  for (int c = threadIdx.x; c < N; c += blockDim.x) {
    float s = 0.f, q = 0.f;
    for (int r = r0; r < r1; r++) { float v = X[(size_t)r * N + c]; s += v; q += v * v; }
    part[((size_t)blockIdx.x * N + c) * 2 + 0] = s;
    part[((size_t)blockIdx.x * N + c) * 2 + 1] = q;
  }
}

__global__ void k_colstat_fin(const float* __restrict__ part, float* __restrict__ stat,
                              int N, int nparts, int M) {
  int c = threadIdx.x;
  if (c >= N) return;
  float s = 0.f, q = 0.f;
  for (int p = 0; p < nparts; p++) {
    s += part[((size_t)p * N + c) * 2 + 0];
    q += part[((size_t)p * N + c) * 2 + 1];
  }
  float m = s / (float)M;
  float var = q / (float)M - m * m;
  stat[c * 2 + 0] = m;
  stat[c * 2 + 1] = rsqrtf(var + 1e-5f);
}

// ---------- normalize h5 (writes f32 + padded f16 copy) ----------
__global__ void k_norm_h5(const float* __restrict__ X, const float* __restrict__ stat,
                          float* __restrict__ h5, _Float16* __restrict__ h5h) {
  int idx = blockIdx.x * 256 + threadIdx.x;
  if (idx >= B_ * 320) return;
  int b = idx / 320, c = idx - b * 320;
  if (c < E_) {
    float v = (X[(size_t)b * E_ + c] - stat[c * 2]) * stat[c * 2 + 1];
    h5[(size_t)b * E_ + c] = v;
    h5h[idx] = (_Float16)v;
  } else {
    h5h[idx] = (_Float16)0.f;
  }
}

// ---------- normalize into hcat at column offset ----------
__global__ void k_norm_to(const float* __restrict__ X, const float* __restrict__ stat,
                          float* __restrict__ Y, int off) {
  int idx = blockIdx.x * 256 + threadIdx.x;
  if (idx >= B_ * E_) return;
  int b = idx / E_, c = idx - b * E_;
  Y[(size_t)b * 600 + off + c] = (X[idx] - stat[c * 2]) * stat[c * 2 + 1];
}

// ---------- big MFMA GEMM, register-built A fragments ----------
// part[ks][b][e] = sum over this split's chunks of h5[b,i]*h5[b,j] * Wg[e,k]
__global__ __launch_bounds__(256, 2) void k_bigmm2(
    const _Float16* __restrict__ Wg, const _Float16* __restrict__ h5h,
    const int* __restrict__ meta, float* __restrict__ part,
    int nchunks, int cps, int kpad2) {
  __shared__ _Float16 h5L[64][328];   // 64 rows x 320 cols (+8 garbage-zeroed), stride 328
  __shared__ _Float16 Ws[160][36];    // [n][k 0..31], stride 36 halves = 18 banks
  __shared__ int metaL[256];
  const int ks = blockIdx.x, mblk = blockIdx.y, nblk = blockIdx.z;
  const int tid = threadIdx.x;
  const int wave = tid >> 6, lane = tid & 63, quad = lane >> 4, l16 = lane & 15;
  const int wm = wave >> 1, wn = wave & 1;
  const int ch0 = ks * cps;
  const int ch1 = min(nchunks, ch0 + cps);

  {
    const _Float16* src = h5h + (size_t)mblk * 64 * 320;
    for (int u = tid; u < 64 * 41; u += 256) {
      int r = u / 41, c8 = u - r * 41;
      h8 v8 = {0, 0, 0, 0, 0, 0, 0, 0};
      if (c8 < 40) v8 = *(const h8*)&src[r * 320 + c8 * 8];
      *(h8*)&h5L[r][c8 * 8] = v8;
    }
    for (int u = tid; u < cps; u += 256)
      metaL[u] = (ch0 + u < nchunks) ? meta[ch0 + u] : 0;
  }
  __syncthreads();

  f4 acc[2][5];
  #pragma unroll
  for (int i = 0; i < 2; i++)
    #pragma unroll
    for (int j = 0; j < 5; j++) acc[i][j] = (f4){0.f, 0.f, 0.f, 0.f};

  for (int ch = ch0; ch < ch1; ch++) {
    const int mt = metaL[ch - ch0];
    const int ii = mt & 0xffff, j0 = mt >> 16;
    const size_t pc = (size_t)ch * 32;
    // stage W tile (160 n x 32 k)
    #pragma unroll
    for (int it = 0; it < 3; it++) {
      int u = tid + it * 256;
      if (u < 640) {
        int n = u >> 2, seg = u & 3;
        *(float4*)&Ws[n][seg * 8] =
            *(const float4*)&Wg[(size_t)(nblk * 160 + n) * kpad2 + pc + seg * 8];
      }
    }
    // A fragments in registers: A[m][k]=h5[m][ii]*h5[m][j0+k] (depends only on h5L)
    h8 af[2];
    #pragma unroll
    for (int mi = 0; mi < 2; mi++) {
      int m = wm * 32 + mi * 16 + l16;
      _Float16 hi = h5L[m][ii];
      h8 vj = *(const h8*)&h5L[m][j0 + quad * 8];
      h8 hs = {hi, hi, hi, hi, hi, hi, hi, hi};
      af[mi] = vj * hs;
    }
    __syncthreads();
    h8 bf[5];
    #pragma unroll
    for (int nt = 0; nt < 5; nt++)
      bf[nt] = *(const h8*)&Ws[wn * 80 + nt * 16 + l16][quad * 8];
    #pragma unroll
    for (int mi = 0; mi < 2; mi++)
      #pragma unroll
      for (int nt = 0; nt < 5; nt++)
        acc[mi][nt] = __builtin_amdgcn_mfma_f32_16x16x32_f16(af[mi], bf[nt], acc[mi][nt], 0, 0, 0);
    __syncthreads();
  }

  float* dst = part + (size_t)ks * (B_ * E_);
  #pragma unroll
  for (int mi = 0; mi < 2; mi++) {
    int b = mblk * 64 + wm * 32 + mi * 16 + quad * 4;
    #pragma unroll
    for (int nt = 0; nt < 5; nt++) {
      int e = nblk * 160 + wn * 80 + nt * 16 + l16;
      if (e < E_) {
        #pragma unroll
        for (int r = 0; r < 4; r++)
          dst[(size_t)(b + r) * E_ + e] = acc[mi][nt][r];
      }
    }
  }
}

// ---------- reduce split-K partials ----------
__global__ void k_reduce(const float* __restrict__ part, float* __restrict__ out) {
  int idx = blockIdx.x * 256 + threadIdx.x;
  if (idx >= B_ * E_) return;
  float s = 0.f;
  #pragma unroll
  for (int k2 = 0; k2 < KSPLIT; k2++) s += part[(size_t)k2 * (B_ * E_) + idx];
  out[idx] = s;
}

extern "C" void kernel_launch(void* const* d_in, const int* in_sizes, int n_in,
                              void* d_out, int out_size, void* d_ws, size_t ws_size,
                              hipStream_t stream) {
  const float* x    = (const float*)d_in[0];
  const float* lemb = (const float*)d_in[1];
  const float* fc1w = (const float*)d_in[2];
  const float* fc1b = (const float*)d_in[3];
  const float* q1   = (const float*)d_in[4];
  const float* fc3w = (const float*)d_in[5];
  const float* fc3b = (const float*)d_in[6];
  const float* q2   = (const float*)d_in[7];
  const float* fc5w = (const float*)d_in[8];
  const float* fc6w = (const float*)d_in[10];
  const float* fc7w = (const float*)d_in[12];
  const float* fc8w = (const float*)d_in[14];
  const float* fc8b = (const float*)d_in[15];
  const float* v    = (const float*)d_in[16];
  float* out = (float*)d_out;
  (void)in_sizes; (void)n_in; (void)out_size; (void)ws_size;

  // chunk enumeration (host-side, deterministic)
  int nchunks = 0;
  for (int i = 0; i < 299; i++) { int js = (i + 1) & ~7; nchunks += (300 - js + 31) >> 5; }
  int cps = (nchunks + KSPLIT - 1) / KSPLIT;
  int kpad2 = nchunks * 32;

  char* base = (char*)d_ws;
  size_t off = 0;
  auto alloc = [&](size_t nbytes) -> char* {
    char* p = base + off;
    off = (off + nbytes + 255) & ~(size_t)255;
    return p;
  };
  // persistent
  int*       meta  = (int*)      alloc((size_t)nchunks * 4);
  _Float16*  Wg    = (_Float16*) alloc((size_t)320 * kpad2 * 2);
  _Float16*  h5h   = (_Float16*) alloc((size_t)B_ * 320 * 2);
  float*     hcat  = (float*)    alloc((size_t)B_ * 600 * 4);
  float*     h7pre = (float*)    alloc((size_t)B_ * E_ * 4);
  float*     out8  = (float*)    alloc((size_t)B_ * E_ * 4);
  float*     cpart = (float*)    alloc((size_t)16 * E_ * 2 * 4);
  float*     cstat = (float*)    alloc((size_t)E_ * 2 * 4);
  // scratch union: phase-1 temporaries overlap split-K partials
  size_t part_bytes = (size_t)KSPLIT * B_ * E_ * 4;   // 19.66 MB
  char* scratch = alloc(part_bytes);
  float* a     = (float*)scratch;                     // [R_][16] = 6.55 MB
  float* sabs  = a + (size_t)R_ * 16;
  float* sstat = sabs + R_;
  float* h     = sstat + 256;
  float* h5pre = h + (size_t)B_ * 600;
  float* h5    = h5pre + (size_t)B_ * E_;
  float* h6pre = h5 + (size_t)B_ * E_;
  float* part  = (float*)scratch;                     // reused after phase-1 dead

  // prep
  hipLaunchKernelGGL(k_meta, dim3(1), dim3(320), 0, stream, meta);
  hipLaunchKernelGGL(k_wg2, dim3(nchunks, 20), dim3(256), 0, stream, fc7w, v, meta, Wg, kpad2);
  // attention pools
  hipLaunchKernelGGL(k_attn2, dim3(R_ / 128), dim3(256), 0, stream, x, fc1w, fc1b, fc3w, fc3b, a, sabs);
  hipLaunchKernelGGL(k_attnstats, dim3(S_, 2), dim3(256), 0, stream, a, sstat);
  hipLaunchKernelGGL(k_pool, dim3(B_), dim3(256), 0, stream, x, a, sabs, sstat, q1, q2, h);
  // fc5 + BN -> h5 (f32 + padded f16)
  hipLaunchKernelGGL(k_gemm_nt, dim3(5, 32), dim3(256), 0, stream, h, fc5w, (const float*)nullptr, h5pre, B_, E_, 600);
  hipLaunchKernelGGL(k_colstat_part, dim3(16), dim3(320), 0, stream, h5pre, cpart, B_, E_);
  hipLaunchKernelGGL(k_colstat_fin, dim3(1), dim3(320), 0, stream, cpart, cstat, E_, 16, B_);
  hipLaunchKernelGGL(k_norm_h5, dim3((B_ * 320) / 256), dim3(256), 0, stream, h5pre, cstat, h5, h5h);
  // fc6 + BN -> hcat[:, :300]
  hipLaunchKernelGGL(k_gemm_nt, dim3(5, 32), dim3(256), 0, stream, h5, fc6w, (const float*)nullptr, h6pre, B_, E_, E_);
  hipLaunchKernelGGL(k_colstat_part, dim3(16), dim3(320), 0, stream, h6pre, cpart, B_, E_);
  hipLaunchKernelGGL(k_colstat_fin, dim3(1), dim3(320), 0, stream, cpart, cstat, E_, 16, B_);
  hipLaunchKernelGGL(k_norm_to, dim3((B_ * E_) / 256), dim3(256), 0, stream, h6pre, cstat, hcat, 0);
  // cross-feature GEMM (f16 MFMA, split-K) + BN -> hcat[:, 300:]
  hipLaunchKernelGGL(k_bigmm2, dim3(KSPLIT, 32, 2), dim3(256), 0, stream, Wg, h5h, meta, part, nchunks, cps, kpad2);
  hipLaunchKernelGGL(k_reduce, dim3((B_ * E_) / 256), dim3(256), 0, stream, part, h7pre);
  hipLaunchKernelGGL(k_colstat_part, dim3(16), dim3(320), 0, stream, h7pre, cpart, B_, E_);
  hipLaunchKernelGGL(k_colstat_fin, dim3(1), dim3(320), 0, stream, cpart, cstat, E_, 16, B_);
  hipLaunchKernelGGL(k_norm_to, dim3((B_ * E_) / 256), dim3(256), 0, stream, h7pre, cstat, hcat, 300);
  // fc8 + label projection
  hipLaunchKernelGGL(k_gemm_nt, dim3(5, 32), dim3(256), 0, stream, hcat, fc8w, fc8b, out8, B_, E_, 600);
  hipLaunchKernelGGL(k_gemm_nt, dim3(16, 32), dim3(256), 0, stream, out8, lemb, (const float*)nullptr, out, B_, 1000, E_);
}